// Round 9
// baseline (479.527 us; speedup 1.0000x reference)
//
#include <hip/hip_runtime.h>
#include <math.h>

typedef float f32x4 __attribute__((ext_vector_type(4)));
typedef short bf16x8 __attribute__((ext_vector_type(8)));

#define BN_EPS 1e-5f

// RNE bf16 split: returns hi bits, rem = v - float(hi)
__device__ __forceinline__ unsigned short bf16_hi(float v, float& rem) {
  unsigned int u = __float_as_uint(v);
  unsigned int r = u + 0x7FFFu + ((u >> 16) & 1u);
  unsigned short h = (unsigned short)(r >> 16);
  rem = v - __uint_as_float((unsigned int)h << 16);
  return h;
}
__device__ __forceinline__ unsigned short bf16_rne(float v) {
  unsigned int u = __float_as_uint(v);
  unsigned int r = u + 0x7FFFu + ((u >> 16) & 1u);
  return (unsigned short)(r >> 16);
}

__device__ __forceinline__ void async_ld16(const unsigned short* g,
                                           unsigned short* l) {
  __builtin_amdgcn_global_load_lds(
      (const __attribute__((address_space(1))) void*)g,
      (__attribute__((address_space(3))) void*)l, 16, 0, 0);
}

// ---------------------------------------------------------------------------
// Fragment chunk convention (verified by R6-R8 passing): one chunk = 512 u16
// = 1KB = one wave's 16x32 bf16 MFMA operand tile; lane (l15=row&15,
// l4=(col&31)>>3) holds 8 u16 at chunk + lane*8.
//
// wbf layout: [k 16][ot16 64][kkb 4][ver 2][512]   (8 MB)
// h2f layout: [b 4][t 128][kkb 4][ver 2][512]      (4 MB, h/m interleaved)
// ---------------------------------------------------------------------------

// ---------------------------------------------------------------------------
// K0: split wb (f32 [16][1024][128]) into fragment-order bf16 hi/lo (wbf).
// grid 1024 x 256; thread = one lane of one (k, ot16, kkb) chunk pair.
// ---------------------------------------------------------------------------
__global__ __launch_bounds__(256) void k0_wbsplit(
    const float* __restrict__ wb, unsigned short* __restrict__ wbf)
{
  int g = blockIdx.x * 256 + threadIdx.x;      // 0..262143
  int l15 = g & 15, l4 = (g >> 4) & 3, kkb = (g >> 6) & 3;
  int ot16 = (g >> 8) & 63, k = g >> 14;

  const float* src = wb + ((size_t)((k << 10) + (ot16 << 4) + l15)) * 128 +
                     (kkb << 5) + (l4 << 3);
  f32x4 v0 = *(const f32x4*)(src);
  f32x4 v1 = *(const f32x4*)(src + 4);

  bf16x8 vh, vm;
  #pragma unroll
  for (int e = 0; e < 8; ++e) {
    float x = (e < 4) ? v0[e] : v1[e - 4];
    float rem;
    vh[e] = (short)bf16_hi(x, rem);
    vm[e] = (short)bf16_rne(rem);
  }
  const int chunk = (k << 9) + (ot16 << 3) + (kkb << 1);  // ver=0
  unsigned short* dst = wbf + ((size_t)chunk << 9) + ((g & 63) << 3);
  *(bf16x8*)(dst) = vh;
  *(bf16x8*)(dst + 512) = vm;
}

// ---------------------------------------------------------------------------
// K1: fused MLP 3->64->128 (BN+ReLU each); writes h2 split bf16 in fragment
// order (h2f). grid 128 x 256; block = (b, 64-point chunk)
// ---------------------------------------------------------------------------
__global__ __launch_bounds__(256) void k1_mlp(
    const float* __restrict__ x,
    const float* __restrict__ w1, const float* __restrict__ g1,
    const float* __restrict__ b1, const float* __restrict__ m1,
    const float* __restrict__ v1,
    const float* __restrict__ w2, const float* __restrict__ g2,
    const float* __restrict__ b2, const float* __restrict__ m2,
    const float* __restrict__ v2,
    unsigned short* __restrict__ h2f)
{
  __shared__ float w1s[64 * 3];
  __shared__ float s1c[64], o1c[64];
  __shared__ float w2s[64 * 132];   // [o][j], padded stride 132
  __shared__ float s2c[128], o2c[128];
  __shared__ float h1s[64 * 64];    // [o][n]

  const int tid = threadIdx.x;
  const int b = blockIdx.x >> 5;
  const int n0 = (blockIdx.x & 31) << 6;

  if (tid < 64) {
    float s = g1[tid] / sqrtf(v1[tid] + BN_EPS);
    s1c[tid] = s;
    o1c[tid] = b1[tid] - m1[tid] * s;
    w1s[tid * 3 + 0] = w1[tid * 3 + 0];
    w1s[tid * 3 + 1] = w1[tid * 3 + 1];
    w1s[tid * 3 + 2] = w1[tid * 3 + 2];
  }
  if (tid < 128) {
    float s = g2[tid] / sqrtf(v2[tid] + BN_EPS);
    s2c[tid] = s;
    o2c[tid] = b2[tid] - m2[tid] * s;
  }
  for (int it = 0; it < 32; ++it) {
    int idx = tid + (it << 8);          // 8192
    int o = idx & 63, j = idx >> 6;
    w2s[o * 132 + j] = w2[j * 64 + o];  // transpose in LDS
  }
  __syncthreads();

  const int n = tid & 63, half = tid >> 6;

  const float* xp = x + ((size_t)(b << 11) + n0 + n) * 3;
  float xv0 = xp[0], xv1 = xp[1], xv2 = xp[2];
  for (int oo = 0; oo < 16; ++oo) {
    int o = (half << 4) + oo;
    float d = xv0 * w1s[o * 3] + xv1 * w1s[o * 3 + 1] + xv2 * w1s[o * 3 + 2];
    d = d * s1c[o] + o1c[o];
    h1s[o * 64 + n] = fmaxf(d, 0.f);
  }
  __syncthreads();

  float acc[32];
  #pragma unroll
  for (int jj = 0; jj < 32; ++jj) acc[jj] = 0.f;
  const int j0 = half << 5;
  for (int o = 0; o < 64; ++o) {
    float a = h1s[o * 64 + n];
    const f32x4* wrow = (const f32x4*)&w2s[o * 132 + j0];
    #pragma unroll
    for (int jg = 0; jg < 8; ++jg) {
      f32x4 wv = wrow[jg];
      acc[jg * 4 + 0] = fmaf(a, wv[0], acc[jg * 4 + 0]);
      acc[jg * 4 + 1] = fmaf(a, wv[1], acc[jg * 4 + 1]);
      acc[jg * 4 + 2] = fmaf(a, wv[2], acc[jg * 4 + 2]);
      acc[jg * 4 + 3] = fmaf(a, wv[3], acc[jg * 4 + 3]);
    }
  }
  // fragment-order store: chunk (b, t=gn>>4, kkb=half), lane row rr=gn&15
  const int gn = n0 + n;
  const int t = gn >> 4, rr = gn & 15;
  const size_t cb = ((size_t)((b * 128 + t) * 4 + half)) << 10;  // *1024 u16
  #pragma unroll
  for (int l4 = 0; l4 < 4; ++l4) {
    bf16x8 vh, vm;
    #pragma unroll
    for (int e = 0; e < 8; ++e) {
      int jj = l4 * 8 + e;
      int j = j0 + jj;
      float vl = fmaxf(acc[jj] * s2c[j] + o2c[j], 0.f);
      float rem;
      vh[e] = (short)bf16_hi(vl, rem);
      vm[e] = (short)bf16_rne(rem);
    }
    *(bf16x8*)(h2f + cb + (l4 << 7) + (rr << 3)) = vh;
    *(bf16x8*)(h2f + cb + 512 + (l4 << 7) + (rr << 3)) = vm;
  }
}

// ---------------------------------------------------------------------------
// K2: feat[b][k][o] = max_n  h2[b,n,:] . wb[k,o,:]  via bf16 3-pass MFMA
// (hh+hm+mh). k-PAIR per block (halves A traffic); W for both branches
// LDS-resident (128 KB, staged via contiguous global_load_lds); A-frags
// loaded as contiguous 1KB wave-chunks from fragment-order h2f with a
// depth-2 static ping-pong (4 named buffer sets). No main-loop barriers.
// grid 256 = 4b x 8kp x 8ot = 1 block/CU, 256 thr (4 waves, 1/SIMD).
// ---------------------------------------------------------------------------
#define MFMA16(a, bv, c) __builtin_amdgcn_mfma_f32_16x16x32_bf16(a, bv, c, 0, 0, 0)

#define LOADP(V0, V1, V2, V3, IT, KS) {                                        \
  const unsigned short* _p = gA + (((size_t)(((IT) << 3) + (w << 1))) << 12) + \
                             ((KS) << 10) + (lane << 3);                       \
  V0 = *(const bf16x8*)(_p);                                                   \
  V1 = *(const bf16x8*)(_p + 512);                                             \
  V2 = *(const bf16x8*)(_p + 4096);                                            \
  V3 = *(const bf16x8*)(_p + 4096 + 512); }

#define PHASE(Ah0, Am0, Ah1, Am1, KS)                                          \
  _Pragma("unroll")                                                            \
  for (int ot2 = 0; ot2 < 8; ++ot2) {                                          \
    const int cb = (((ot2 << 3) + ((KS) << 1)) << 9) + (lane << 3);            \
    bf16x8 b0h = *(const bf16x8*)(&Wl[0][cb]);                                 \
    bf16x8 b0m = *(const bf16x8*)(&Wl[0][cb + 512]);                           \
    bf16x8 b1h = *(const bf16x8*)(&Wl[1][cb]);                                 \
    bf16x8 b1m = *(const bf16x8*)(&Wl[1][cb + 512]);                           \
    acc00[ot2] = MFMA16(Ah0, b0h, acc00[ot2]);                                 \
    acc01[ot2] = MFMA16(Ah1, b0h, acc01[ot2]);                                 \
    acc10[ot2] = MFMA16(Ah0, b1h, acc10[ot2]);                                 \
    acc11[ot2] = MFMA16(Ah1, b1h, acc11[ot2]);                                 \
    acc00[ot2] = MFMA16(Ah0, b0m, acc00[ot2]);                                 \
    acc01[ot2] = MFMA16(Ah1, b0m, acc01[ot2]);                                 \
    acc10[ot2] = MFMA16(Ah0, b1m, acc10[ot2]);                                 \
    acc11[ot2] = MFMA16(Ah1, b1m, acc11[ot2]);                                 \
    acc00[ot2] = MFMA16(Am0, b0h, acc00[ot2]);                                 \
    acc01[ot2] = MFMA16(Am1, b0h, acc01[ot2]);                                 \
    acc10[ot2] = MFMA16(Am0, b1h, acc10[ot2]);                                 \
    acc11[ot2] = MFMA16(Am1, b1h, acc11[ot2]);                                 \
  }

__global__ __launch_bounds__(256, 1) void k2_mfma(
    const unsigned short* __restrict__ h2f,   // [4][128][4][2][512]
    const unsigned short* __restrict__ wbf,   // [16][64][4][2][512]
    float* __restrict__ feat)                 // [4][16][1024]
{
  __shared__ unsigned short Wl[2][32768];     // 128 KB: [kk][ot2][kkb][ver][512]
  __shared__ float redm[2][4][128];

  const int tid = threadIdx.x;
  const int bid = blockIdx.x;
  const int ot = bid & 7;
  const int kp = (bid >> 3) & 7;
  const int b  = bid >> 6;
  const int o0 = ot << 7;
  const int lane = tid & 63, w = tid >> 6;

  // stage W for both branches: contiguous 64 KB each via global_load_lds
  #pragma unroll
  for (int kk = 0; kk < 2; ++kk) {
    const unsigned short* src =
        wbf + ((size_t)((((kp << 1) + kk) << 9) + (ot << 6)) << 9);
    for (int it = 0; it < 16; ++it) {
      int seg = (it << 2) + w;                 // 64 segs of 1KB, 16 per wave
      async_ld16(src + (seg << 9) + (lane << 3), &Wl[kk][seg << 9]);
    }
  }

  const unsigned short* gA = h2f + ((size_t)b << 19);

  bf16x8 P00, P01, P02, P03, P10, P11, P12, P13;
  bf16x8 P20, P21, P22, P23, P30, P31, P32, P33;
  LOADP(P00, P01, P02, P03, 0, 0);
  LOADP(P10, P11, P12, P13, 0, 1);

  float mx0[8], mx1[8];
  #pragma unroll
  for (int j = 0; j < 8; ++j) { mx0[j] = -3.4e38f; mx1[j] = -3.4e38f; }

  __syncthreads();   // drains W staging (vmcnt) + barrier

  for (int itn = 0; itn < 16; ++itn) {
    const int tn = (itn < 15) ? itn + 1 : 15;

    f32x4 acc00[8], acc01[8], acc10[8], acc11[8];
    #pragma unroll
    for (int j = 0; j < 8; ++j) {
      f32x4 z = {0.f, 0.f, 0.f, 0.f};
      acc00[j] = z; acc01[j] = z; acc10[j] = z; acc11[j] = z;
    }

    LOADP(P20, P21, P22, P23, itn, 2);
    PHASE(P00, P01, P02, P03, 0);
    LOADP(P30, P31, P32, P33, itn, 3);
    PHASE(P10, P11, P12, P13, 1);
    LOADP(P00, P01, P02, P03, tn, 0);
    PHASE(P20, P21, P22, P23, 2);
    LOADP(P10, P11, P12, P13, tn, 1);
    PHASE(P30, P31, P32, P33, 3);

    #pragma unroll
    for (int ot2 = 0; ot2 < 8; ++ot2) {
      f32x4 a = acc00[ot2], c = acc01[ot2];
      float m0 = fmaxf(fmaxf(a[0], a[1]), fmaxf(a[2], a[3]));
      float m1 = fmaxf(fmaxf(c[0], c[1]), fmaxf(c[2], c[3]));
      mx0[ot2] = fmaxf(mx0[ot2], fmaxf(m0, m1));
      f32x4 d = acc10[ot2], e = acc11[ot2];
      float m2 = fmaxf(fmaxf(d[0], d[1]), fmaxf(d[2], d[3]));
      float m3 = fmaxf(fmaxf(e[0], e[1]), fmaxf(e[2], e[3]));
      mx1[ot2] = fmaxf(mx1[ot2], fmaxf(m2, m3));
    }
  }

  // cross-lane: fold l4 groups (rows) -> per-col max
  #pragma unroll
  for (int ot2 = 0; ot2 < 8; ++ot2) {
    float m = mx0[ot2];
    m = fmaxf(m, __shfl_xor(m, 16));
    m = fmaxf(m, __shfl_xor(m, 32));
    mx0[ot2] = m;
    float q = mx1[ot2];
    q = fmaxf(q, __shfl_xor(q, 16));
    q = fmaxf(q, __shfl_xor(q, 32));
    mx1[ot2] = q;
  }
  if (lane < 16) {
    #pragma unroll
    for (int ot2 = 0; ot2 < 8; ++ot2) {
      redm[0][w][(ot2 << 4) + lane] = mx0[ot2];
      redm[1][w][(ot2 << 4) + lane] = mx1[ot2];
    }
  }
  __syncthreads();
  {
    int kk = tid >> 7, o = tid & 127;
    float m = fmaxf(fmaxf(redm[kk][0][o], redm[kk][1][o]),
                    fmaxf(redm[kk][2][o], redm[kk][3][o]));
    feat[((size_t)(b * 16 + (kp << 1) + kk) << 10) + o0 + o] = m;
  }
}

// ---------------------------------------------------------------------------
// K3a: caps[b][i][e] = squash_e( BN(feat[b][e][i]) ),  e=16. grid 16 x 256
// ---------------------------------------------------------------------------
__global__ __launch_bounds__(256) void k3a_caps(
    const float* __restrict__ feat,
    const float* __restrict__ gb, const float* __restrict__ bb,
    const float* __restrict__ mb, const float* __restrict__ vb,
    float* __restrict__ caps)
{
  int g = blockIdx.x * 256 + threadIdx.x;  // 4096
  int b = g >> 10, i = g & 1023;
  float val[16];
  float ss = 0.f;
  #pragma unroll
  for (int e = 0; e < 16; ++e) {
    int ei = (e << 10) + i;
    float f = feat[((size_t)(b << 4) << 10) + ei];
    float sc = gb[ei] / sqrtf(vb[ei] + BN_EPS);
    float vv = (f - mb[ei]) * sc + bb[ei];
    val[e] = vv;
    ss += vv * vv;
  }
  float nrm = sqrtf(ss);
  float scl = nrm / (1.f + nrm * nrm);
  f32x4* cp = (f32x4*)&caps[(size_t)((b << 10) + i) << 4];
  #pragma unroll
  for (int q = 0; q < 4; ++q) {
    f32x4 v;
    v[0] = val[q * 4 + 0] * scl; v[1] = val[q * 4 + 1] * scl;
    v[2] = val[q * 4 + 2] * scl; v[3] = val[q * 4 + 3] * scl;
    cp[q] = v;
  }
}

// ---------------------------------------------------------------------------
// K3b: u[b][o][i][v] = sum_e caps[b][i][e] * Wc[o][i][e][v]
//      + partial s0 per (o, i-tile). grid 1024 (o=32 x itile=32), 256 thr
// ---------------------------------------------------------------------------
__global__ __launch_bounds__(256) void k3b_u(
    const float* __restrict__ caps, const float* __restrict__ Wc,
    float* __restrict__ u, float* __restrict__ s0p)
{
  __shared__ float caps_l[4 * 32 * 16];  // [b][il][e]
  __shared__ float s_red[16 * 32];       // [w*4+b][v]

  const int tid = threadIdx.x;
  const int o = blockIdx.x & 31, it = blockIdx.x >> 5;
  const int i0 = it << 5;

  for (int ld = 0; ld < 8; ++ld) {
    int idx = tid + (ld << 8);  // 2048 = b*512 + il*16 + e
    int bq = idx >> 9, il = (idx >> 4) & 31, e = idx & 15;
    caps_l[idx] = caps[(size_t)(((bq << 10) + i0 + il) << 4) + e];
  }
  __syncthreads();

  const int w = tid >> 6, lane = tid & 63;
  const int eh = lane >> 5, v = lane & 31;
  float s0acc[4] = {0.f, 0.f, 0.f, 0.f};

  for (int ii = 0; ii < 8; ++ii) {
    int il = (w << 3) + ii;
    int i = i0 + il;
    const float* wc = Wc + ((size_t)(o << 10) + i) * 512 + (eh << 8) + v;
    float acc[4] = {0.f, 0.f, 0.f, 0.f};
    #pragma unroll
    for (int ee = 0; ee < 8; ++ee) {
      float wv = wc[ee * 32];
      int e = (eh << 3) + ee;
      #pragma unroll
      for (int bq = 0; bq < 4; ++bq)
        acc[bq] = fmaf(caps_l[bq * 512 + il * 16 + e], wv, acc[bq]);
    }
    #pragma unroll
    for (int bq = 0; bq < 4; ++bq) {
      acc[bq] += __shfl_xor(acc[bq], 32);
      if (eh == 0) {
        u[(size_t)((((bq << 5) + o) << 10) + i) * 32 + v] = acc[bq];
        s0acc[bq] += acc[bq];
      }
    }
  }
  if (eh == 0) {
    #pragma unroll
    for (int bq = 0; bq < 4; ++bq) s_red[((w << 2) + bq) * 32 + v] = s0acc[bq];
  }
  __syncthreads();
  if (tid < 128) {
    int bq = tid >> 5, vv = tid & 31;
    float s = s_red[bq * 32 + vv] + s_red[(4 + bq) * 32 + vv] +
              s_red[(8 + bq) * 32 + vv] + s_red[(12 + bq) * 32 + vv];
    s0p[(size_t)(((bq << 5) + it) << 5 | o) * 32 + vv] = s;
  }
}

// ---------------------------------------------------------------------------
// K4: out = squash_v( prescale * sum_it spart[b][it][o][v] ). grid 4 x 256
// ---------------------------------------------------------------------------
__global__ __launch_bounds__(256) void k4_squash(
    const float* __restrict__ sp, float* __restrict__ out, float prescale)
{
  const int tid = threadIdx.x;
  const int b = blockIdx.x;
  const int o = tid >> 3, vq = (tid & 7) << 2;
  f32x4 acc = {0.f, 0.f, 0.f, 0.f};
  for (int it = 0; it < 32; ++it) {
    f32x4 p = *(const f32x4*)(sp + (size_t)(((b << 5) + it) << 5 | o) * 32 + vq);
    acc += p;
  }
  acc *= prescale;
  float ss = acc[0] * acc[0] + acc[1] * acc[1] + acc[2] * acc[2] + acc[3] * acc[3];
  ss += __shfl_xor(ss, 1);
  ss += __shfl_xor(ss, 2);
  ss += __shfl_xor(ss, 4);
  float nrm = sqrtf(ss);
  float scl = nrm / (1.f + nrm * nrm);
  f32x4 r = acc * scl;
  *(f32x4*)(out + (size_t)((b << 5) + o) * 32 + vq) = r;
}

// ---------------------------------------------------------------------------
// K5: one routing pass over u. grid 128 (b=4 x itile=32), 256 thr
// ---------------------------------------------------------------------------
__global__ __launch_bounds__(256) void k5_route(
    const float* __restrict__ u, const float* __restrict__ aprev,
    const float* __restrict__ bprev, float* __restrict__ bout,
    float* __restrict__ spart, int pass)
{
  __shared__ float a_l[32 * 33];
  __shared__ float u_l[4 * 32 * 33];
  __shared__ float s_red[4 * 32 * 33];

  const int tid = threadIdx.x;
  const int b = blockIdx.x >> 5, it = blockIdx.x & 31;
  const int i0 = it << 5;

  for (int ld = 0; ld < 4; ++ld) {
    int idx = tid + (ld << 8);  // 1024
    int o = idx >> 5, v = idx & 31;
    a_l[o * 33 + v] = aprev[((b << 5) + o) * 32 + v];
  }
  __syncthreads();

  const int w = tid >> 6, lane = tid & 63;
  const int ln5 = lane & 31, hb = lane >> 5;
  float* uw = &u_l[w * 1056];

  float sacc[16];
  #pragma unroll
  for (int q = 0; q < 16; ++q) sacc[q] = 0.f;

  for (int ii = 0; ii < 8; ++ii) {
    int i = i0 + (w << 3) + ii;
    #pragma unroll
    for (int rr = 0; rr < 16; ++rr) {
      int o = (rr << 1) + hb;
      uw[o * 33 + ln5] = u[(size_t)((((b << 5) + o) << 10) + i) * 32 + ln5];
    }
    float ag = 0.f;
    #pragma unroll
    for (int q = 0; q < 16; ++q) {
      int vv = (hb << 4) + q;
      ag = fmaf(a_l[ln5 * 33 + vv], uw[ln5 * 33 + vv], ag);
    }
    ag += __shfl_xor(ag, 32);
    float bl = ag;
    if (pass == 1) bl += bprev[(((b << 5) + ln5) << 10) + i];
    if (pass == 0 && hb == 0) bout[(((b << 5) + ln5) << 10) + i] = bl;
    float m = bl;
    m = fmaxf(m, __shfl_xor(m, 1));
    m = fmaxf(m, __shfl_xor(m, 2));
    m = fmaxf(m, __shfl_xor(m, 4));
    m = fmaxf(m, __shfl_xor(m, 8));
    m = fmaxf(m, __shfl_xor(m, 16));
    float e = expf(bl - m);
    float sm = e;
    sm += __shfl_xor(sm, 1);
    sm += __shfl_xor(sm, 2);
    sm += __shfl_xor(sm, 4);
    sm += __shfl_xor(sm, 8);
    sm += __shfl_xor(sm, 16);
    float c = e / sm;
    #pragma unroll
    for (int q = 0; q < 16; ++q) {
      int vv = (hb << 4) + q;
      sacc[q] = fmaf(c, uw[ln5 * 33 + vv], sacc[q]);
    }
  }
  #pragma unroll
  for (int q = 0; q < 16; ++q)
    s_red[w * 1056 + ln5 * 33 + (hb << 4) + q] = sacc[q];
  __syncthreads();
  for (int ld = 0; ld < 4; ++ld) {
    int idx = tid + (ld << 8);
    int o = idx >> 5, vv = idx & 31;
    float s = s_red[o * 33 + vv] + s_red[1056 + o * 33 + vv] +
              s_red[2112 + o * 33 + vv] + s_red[3168 + o * 33 + vv];
    spart[(size_t)(((b << 5) + it) << 5 | o) * 32 + vv] = s;
  }
}

// ---------------------------------------------------------------------------
extern "C" void kernel_launch(void* const* d_in, const int* in_sizes, int n_in,
                              void* d_out, int out_size, void* d_ws, size_t ws_size,
                              hipStream_t stream) {
  const float* x  = (const float*)d_in[0];
  const float* w1 = (const float*)d_in[1];
  const float* g1 = (const float*)d_in[2];
  const float* b1 = (const float*)d_in[3];
  const float* m1 = (const float*)d_in[4];
  const float* v1 = (const float*)d_in[5];
  const float* w2 = (const float*)d_in[6];
  const float* g2 = (const float*)d_in[7];
  const float* b2 = (const float*)d_in[8];
  const float* m2 = (const float*)d_in[9];
  const float* v2 = (const float*)d_in[10];
  const float* wb = (const float*)d_in[11];
  const float* gb = (const float*)d_in[12];
  const float* bb = (const float*)d_in[13];
  const float* mb = (const float*)d_in[14];
  const float* vb = (const float*)d_in[15];
  const float* Wc = (const float*)d_in[16];
  float* out = (float*)d_out;
  float* ws = (float*)d_ws;

  // workspace (float units). h2f (1,048,576 f) + wbf (2,097,152 f) live in
  // the first 3,145,728 floats, DEAD after k2; u (4,194,304 f) aliases them.
  unsigned short* h2f = (unsigned short*)(ws);              // 2,097,152 u16
  unsigned short* wbf = (unsigned short*)(ws + 1048576);    // 4,194,304 u16
  float* u    = ws;             // aliases h2f/wbf (k3b runs after k2)
  float* feat = ws + 4194304;   // 65536
  float* caps = ws + 4259840;   // 65536
  float* s0p  = ws + 4325376;   // 131072
  float* s1p  = ws + 4456448;   // 131072
  float* s2p  = ws + 4587520;   // 131072
  float* a0   = ws + 4718592;   // 4096
  float* a1   = ws + 4722688;   // 4096
  float* b1l  = ws + 4726784;   // 131072

  k0_wbsplit<<<1024, 256, 0, stream>>>(wb, wbf);
  k1_mlp<<<128, 256, 0, stream>>>(x, w1, g1, b1, m1, v1,
                                  w2, g2, b2, m2, v2, h2f);
  k2_mfma<<<256, 256, 0, stream>>>(h2f, wbf, feat);
  k3a_caps<<<16, 256, 0, stream>>>(feat, gb, bb, mb, vb, caps);
  k3b_u<<<1024, 256, 0, stream>>>(caps, Wc, u, s0p);
  k4_squash<<<4, 256, 0, stream>>>(s0p, a0, 1.f / 32.f);
  k5_route<<<128, 256, 0, stream>>>(u, a0, b1l, b1l, s1p, 0);
  k4_squash<<<4, 256, 0, stream>>>(s1p, a1, 1.f);
  k5_route<<<128, 256, 0, stream>>>(u, a1, b1l, b1l, s2p, 1);
  k4_squash<<<4, 256, 0, stream>>>(s2p, out, 1.f);
}